// Round 2
// baseline (636.313 us; speedup 1.0000x reference)
//
#include <hip/hip_runtime.h>
#include <math.h>

// DSSIM (mean), B=32 C=3 H=W=512 fp32, separable 11x11 Gaussian.
// R6 = R5 geometry (RB=32, RING=42, LDS 29.6KB -> 5 blocks/CU) with the
// register-spill fixed:
//  - R5 spilled (VGPR 48, WRITE_SIZE 61.6 MB scratch): a20/b20 arrays (40
//    regs) + accs exceeded the (256,5) cap of ~102.
//  - h-task restructured: NO staging arrays. Load one float4 pair per
//    4-element group and FMA elements directly into the packed output
//    accumulators (peak live data = 8 floats).
//  - cross term blur(ab) via identity (blur((a+b)^2)-blur(a^2)-blur(b^2))/2
//    so no pass ever needs both full rows co-live.
//  - everything else (v-phase, ring, grid 6144, block reduce) = R5.
//  - NO lambdas/helpers (R3: un-inlined helpers demote arrays to scratch);
//    shared h-accumulate code via a do{}while(0) macro with static guards.

namespace {
constexpr int IMG = 512;
constexpr int TW = 32;                 // strip width
constexpr int RB = 32;                 // output rows per chunk
constexpr int RING = RB + 10;          // 42 ring rows
constexpr int SLOT = 44;               // floats per (xg, ringrow) slot
constexpr int XGN = TW / 8;            // 4 col-groups
constexpr int SEGR = 128;              // rows per block segment
constexpr int NCHUNK = SEGR / RB;      // 4 chunks per segment
constexpr int SEGN = IMG / SEGR;       // 4 segments per strip
constexpr int CTILES = IMG / TW;       // 16 strips per image
constexpr int NIMG = 96;               // 32*3
constexpr float C1c = 1e-4f;
constexpr float C2c = 9e-4f;
constexpr float INV_N = 1.0f / 25165824.0f;  // 1/(96*512*512)
}

typedef float v2f __attribute__((ext_vector_type(2)));

__global__ void dssim_zero(float* ws) { ws[0] = 0.0f; }

__global__ void dssim_final(const float* __restrict__ ws, float* __restrict__ out) {
  out[0] = ws[0] * INV_N;
}

// h-phase accumulate of one element (i static): quantities {a, b, a^2, b^2,
// (a+b)^2} into packed col-pair accumulators. jp'=0 active for i in [3,14]
// (m=i-3), jp'=1 for i in [5,16] (m=i-5). Dead paths fold at compile time.
#define ACC_H(I, VA, VB) do {                                              \
    const int i_ = (I);                                                    \
    float va_ = (VA), vb_ = (VB);                                          \
    float pa_ = va_ * va_, pb_ = vb_ * vb_;                                \
    float sa_ = va_ + vb_;                                                 \
    float ps_ = sa_ * sa_;                                                 \
    v2f va2_; va2_.x = va_; va2_.y = va_;                                  \
    v2f vb2_; vb2_.x = vb_; vb2_.y = vb_;                                  \
    v2f pa2_; pa2_.x = pa_; pa2_.y = pa_;                                  \
    v2f pb2_; pb2_.x = pb_; pb2_.y = pb_;                                  \
    v2f ps2_; ps2_.x = ps_; ps2_.y = ps_;                                  \
    if (i_ >= 3 && i_ <= 14) {                                             \
      v2f w_ = wp[i_ - 3];                                                 \
      o0[0] = __builtin_elementwise_fma(w_, va2_, o0[0]);                  \
      o1[0] = __builtin_elementwise_fma(w_, vb2_, o1[0]);                  \
      o2[0] = __builtin_elementwise_fma(w_, pa2_, o2[0]);                  \
      o3[0] = __builtin_elementwise_fma(w_, pb2_, o3[0]);                  \
      oS[0] = __builtin_elementwise_fma(w_, ps2_, oS[0]);                  \
    }                                                                      \
    if (i_ >= 5 && i_ <= 16) {                                             \
      v2f w_ = wp[i_ - 5];                                                 \
      o0[1] = __builtin_elementwise_fma(w_, va2_, o0[1]);                  \
      o1[1] = __builtin_elementwise_fma(w_, vb2_, o1[1]);                  \
      o2[1] = __builtin_elementwise_fma(w_, pa2_, o2[1]);                  \
      o3[1] = __builtin_elementwise_fma(w_, pb2_, o3[1]);                  \
      oS[1] = __builtin_elementwise_fma(w_, ps2_, oS[1]);                  \
    }                                                                      \
  } while (0)

__global__ __launch_bounds__(256, 5) void dssim_main(
    const float* __restrict__ im1, const float* __restrict__ im2,
    const float* __restrict__ gk, float* __restrict__ ws)
{
  __shared__ float sR[XGN * RING * SLOT];   // 29,568 B -> 5 blocks/CU

  const int tid = threadIdx.x;
  const int bid = blockIdx.x;
  const int img = bid >> 6;          // 64 blocks per image (16 strips x 4 segs)
  const int rem = bid & 63;
  const int tsx = rem & 15;
  const int seg = rem >> 4;
  const int X0s = tsx * TW;
  const int Y0  = seg * SEGR;

  const float* __restrict__ p1 = im1 + (size_t)img * (IMG * IMG);
  const float* __restrict__ p2 = im2 + (size_t)img * (IMG * IMG);

  // k1[i] = k2d[i][5] / sqrt(k2d[5][5])  (separable, sum(k1)=1)
  float wt[11];
  {
    float ic = 1.0f / sqrtf(gk[5 * 11 + 5]);
    #pragma unroll
    for (int i = 0; i < 11; ++i) wt[i] = gk[i * 11 + 5] * ic;
  }
  // packed weight pairs: wp[m] = {wte(m), wte(m-1)}, wte zero-padded
  v2f wp[12];
  #pragma unroll
  for (int m = 0; m < 12; ++m) {
    float lo = (m <= 10) ? wt[m] : 0.f;
    float hi = (m >= 1) ? wt[m - 1] : 0.f;
    wp[m].x = lo; wp[m].y = hi;
  }

  // v-phase mapping: one column per thread, 4 rows (2 packed pairs)
  const int c   = tid & 31;
  const int yg  = tid >> 5;          // 0..7
  const int xg3 = c >> 3;
  const int cl  = c & 7;

  float lsum = 0.f;

  for (int kc = 0; kc < NCHUNK; ++kc) {
    // ---- h-phase: produce new h-rows into the ring ----
    const int r0    = (kc == 0) ? -5 : RB * kc + 5;        // local row
    const int ntask = (kc == 0) ? 8 * RING : 8 * RB;       // 336 / 256
    for (int t = tid; t < ntask; t += 256) {
      const int colsub = t & 7;
      const int dr  = t >> 3;
      const int rl  = r0 + dr;                 // local row in [-5, SEGR+4]
      const int ry  = Y0 + rl;                 // global row
      const int rr  = (rl + 5) % RING;         // ring slot row
      const int xg  = colsub >> 1;
      const int sub = colsub & 1;
      const int cbs = X0s + xg * 8 + sub * 4 - 8;  // window col of elem 0, 4-aligned

      v2f o0[2], o1[2], o2[2], o3[2], oS[2];
      #pragma unroll
      for (int jp = 0; jp < 2; ++jp) {
        o0[jp] = 0.f; o1[jp] = 0.f; o2[jp] = 0.f; o3[jp] = 0.f; oS[jp] = 0.f;
      }

      if ((unsigned)ry < (unsigned)IMG) {
        const float* row1 = p1 + (size_t)ry * IMG;
        const float* row2 = p2 + (size_t)ry * IMG;
        if (cbs >= 0 && cbs + 20 <= IMG) {
          #pragma unroll
          for (int g = 0; g < 5; ++g) {
            float4 va4 = *(const float4*)(row1 + cbs + 4 * g);
            float4 vb4 = *(const float4*)(row2 + cbs + 4 * g);
            ACC_H(4 * g + 0, va4.x, vb4.x);
            ACC_H(4 * g + 1, va4.y, vb4.y);
            ACC_H(4 * g + 2, va4.z, vb4.z);
            ACC_H(4 * g + 3, va4.w, vb4.w);
          }
        } else {
          #pragma unroll
          for (int i = 3; i <= 16; ++i) {
            int cc = cbs + i;
            float va = 0.f, vb = 0.f;
            if ((unsigned)cc < (unsigned)IMG) { va = row1[cc]; vb = row2[cc]; }
            ACC_H(i, va, vb);
          }
        }
      }
      // blur(ab) = (blur((a+b)^2) - blur(a^2) - blur(b^2)) / 2
      v2f o4a = (oS[0] - o2[0] - o3[0]) * 0.5f;
      v2f o4b = (oS[1] - o2[1] - o3[1]) * 0.5f;

      const int base  = (xg * RING + rr) * SLOT;
      const int jbase = base + 16 * sub;       // global jpg = 2*sub + jp'
      *(float4*)&sR[jbase]      = make_float4(o0[0].x, o1[0].x, o2[0].x, o3[0].x);
      *(float4*)&sR[jbase + 4]  = make_float4(o0[0].y, o1[0].y, o2[0].y, o3[0].y);
      *(float4*)&sR[jbase + 8]  = make_float4(o0[1].x, o1[1].x, o2[1].x, o3[1].x);
      *(float4*)&sR[jbase + 12] = make_float4(o0[1].y, o1[1].y, o2[1].y, o3[1].y);
      *(float4*)&sR[base + 32 + 4 * sub] = make_float4(o4a.x, o4a.y, o4b.x, o4b.y);
    }
    __syncthreads();

    // ---- v-phase: 4 output rows per thread (2 packed pairs) + SSIM ----
    v2f m1p[2], m2p[2], e11p[2], e22p[2], e12p[2];
    #pragma unroll
    for (int jp = 0; jp < 2; ++jp) {
      m1p[jp] = 0.f; m2p[jp] = 0.f; e11p[jp] = 0.f; e22p[jp] = 0.f; e12p[jp] = 0.f;
    }

    const int y0l = RB * kc + yg * 4;          // local first output row
    int idx = y0l % RING;
    #pragma unroll
    for (int rr = 0; rr < 14; ++rr) {
      const int a = (xg3 * RING + idx) * SLOT;
      float4 v4 = *(const float4*)&sR[a + 4 * cl];
      float  v5 = sR[a + 32 + cl];
      v2f x1; x1.x = v4.x; x1.y = v4.x;
      v2f x2; x2.x = v4.y; x2.y = v4.y;
      v2f x3; x3.x = v4.z; x3.y = v4.z;
      v2f x4; x4.x = v4.w; x4.y = v4.w;
      v2f x5; x5.x = v5;   x5.y = v5;
      if (rr < 12) {                           // jp=0, m = rr
        v2f w = wp[rr];
        m1p[0]  = __builtin_elementwise_fma(w, x1, m1p[0]);
        m2p[0]  = __builtin_elementwise_fma(w, x2, m2p[0]);
        e11p[0] = __builtin_elementwise_fma(w, x3, e11p[0]);
        e22p[0] = __builtin_elementwise_fma(w, x4, e22p[0]);
        e12p[0] = __builtin_elementwise_fma(w, x5, e12p[0]);
      }
      if (rr >= 2) {                           // jp=1, m = rr-2
        v2f w = wp[rr - 2];
        m1p[1]  = __builtin_elementwise_fma(w, x1, m1p[1]);
        m2p[1]  = __builtin_elementwise_fma(w, x2, m2p[1]);
        e11p[1] = __builtin_elementwise_fma(w, x3, e11p[1]);
        e22p[1] = __builtin_elementwise_fma(w, x4, e22p[1]);
        e12p[1] = __builtin_elementwise_fma(w, x5, e12p[1]);
      }
      idx++; if (idx == RING) idx = 0;
    }

    #pragma unroll
    for (int jp = 0; jp < 2; ++jp) {
      v2f m1 = m1p[jp], m2 = m2p[jp];
      v2f m1s = m1 * m1, m2s = m2 * m2, m12 = m1 * m2;
      v2f s11 = e11p[jp] - m1s, s22 = e22p[jp] - m2s, s12 = e12p[jp] - m12;
      v2f num = (2.f * m12 + C1c) * (2.f * s12 + C2c);
      v2f den = (m1s + m2s + C1c) * (s11 + s22 + C2c);
      lsum += (1.f - num.x * __builtin_amdgcn_rcpf(den.x)) * 0.5f;
      lsum += (1.f - num.y * __builtin_amdgcn_rcpf(den.y)) * 0.5f;
    }
    __syncthreads();
  }

  // wave reduce -> block reduce -> ONE atomic per block (6144 total)
  #pragma unroll
  for (int off = 32; off > 0; off >>= 1) lsum += __shfl_down(lsum, off);
  if ((tid & 63) == 0) sR[tid >> 6] = lsum;
  __syncthreads();
  if (tid == 0) atomicAdd(ws, sR[0] + sR[1] + sR[2] + sR[3]);
}

extern "C" void kernel_launch(void* const* d_in, const int* in_sizes, int n_in,
                              void* d_out, int out_size, void* d_ws, size_t ws_size,
                              hipStream_t stream) {
  const float* im1 = (const float*)d_in[0];
  const float* im2 = (const float*)d_in[1];
  const float* gk  = (const float*)d_in[2];
  float* out = (float*)d_out;
  float* ws  = (float*)d_ws;

  hipLaunchKernelGGL(dssim_zero, dim3(1), dim3(1), 0, stream, ws);
  hipLaunchKernelGGL(dssim_main, dim3(NIMG * CTILES * SEGN), dim3(256), 0, stream,
                     im1, im2, gk, ws);
  hipLaunchKernelGGL(dssim_final, dim3(1), dim3(1), 0, stream, ws, out);
}

// Round 3
// 284.521 us; speedup vs baseline: 2.2364x; 2.2364x over previous
//
#include <hip/hip_runtime.h>
#include <math.h>

// DSSIM (mean), B=32 C=3 H=W=512 fp32, separable 11x11 Gaussian.
// R7 = R5 code (RB=32, RING=42, LDS 29.7KB, 6144 blocks) with the spill
// fixed by RELAXING the launch bound:
//  - R5/R6 post-mortem: __launch_bounds__(256,5) caps VGPR at ~96-102; the
//    allocator fails to color the unrolled conv body and spills (VGPR=48,
//    scratch FETCH up to 1GB, WRITE up to 560MB, dur 517us).
//  - Occupancy target (5 blocks/CU) is already delivered by LDS = 29.7KB;
//    at the natural ~76-100 VGPRs the register file allows >=5 waves/SIMD,
//    so the cap buys nothing. Use (256,4): cap 128, no spill, LDS-bound
//    occupancy 20 waves/CU.
//  - everything else identical to R5 (which PASSED): h-phase as 8 col-
//    subtasks x 32 rows (all 256 threads busy), packed-FP32 v2f math,
//    4-segment strips, one atomicAdd per block.
//  - NO lambdas/helpers (R3: un-inlined helpers demote arrays to scratch).

namespace {
constexpr int IMG = 512;
constexpr int TW = 32;                 // strip width
constexpr int RB = 32;                 // output rows per chunk
constexpr int RING = RB + 10;          // 42 ring rows
constexpr int SLOT = 44;               // floats per (xg, ringrow) slot
constexpr int XGN = TW / 8;            // 4 col-groups
constexpr int SEGR = 128;              // rows per block segment
constexpr int NCHUNK = SEGR / RB;      // 4 chunks per segment
constexpr int SEGN = IMG / SEGR;       // 4 segments per strip
constexpr int CTILES = IMG / TW;       // 16 strips per image
constexpr int NIMG = 96;               // 32*3
constexpr float C1c = 1e-4f;
constexpr float C2c = 9e-4f;
constexpr float INV_N = 1.0f / 25165824.0f;  // 1/(96*512*512)
}

typedef float v2f __attribute__((ext_vector_type(2)));

__global__ void dssim_zero(float* ws) { ws[0] = 0.0f; }

__global__ void dssim_final(const float* __restrict__ ws, float* __restrict__ out) {
  out[0] = ws[0] * INV_N;
}

__global__ __launch_bounds__(256, 4) void dssim_main(
    const float* __restrict__ im1, const float* __restrict__ im2,
    const float* __restrict__ gk, float* __restrict__ ws)
{
  __shared__ float sR[XGN * RING * SLOT];   // 29,568 B -> 5 blocks/CU (LDS-bound)

  const int tid = threadIdx.x;
  const int bid = blockIdx.x;
  const int img = bid >> 6;          // 64 blocks per image (16 strips x 4 segs)
  const int rem = bid & 63;
  const int tsx = rem & 15;
  const int seg = rem >> 4;
  const int X0s = tsx * TW;
  const int Y0  = seg * SEGR;

  const float* __restrict__ p1 = im1 + (size_t)img * (IMG * IMG);
  const float* __restrict__ p2 = im2 + (size_t)img * (IMG * IMG);

  // k1[i] = k2d[i][5] / sqrt(k2d[5][5])  (separable, sum(k1)=1)
  float wt[11];
  {
    float ic = 1.0f / sqrtf(gk[5 * 11 + 5]);
    #pragma unroll
    for (int i = 0; i < 11; ++i) wt[i] = gk[i * 11 + 5] * ic;
  }
  // packed weight pairs: wp[m] = {wte(m), wte(m-1)}, wte zero-padded
  v2f wp[12];
  #pragma unroll
  for (int m = 0; m < 12; ++m) {
    float lo = (m <= 10) ? wt[m] : 0.f;
    float hi = (m >= 1) ? wt[m - 1] : 0.f;
    wp[m].x = lo; wp[m].y = hi;
  }

  // v-phase mapping: one column per thread, 4 rows (2 packed pairs)
  const int c   = tid & 31;
  const int yg  = tid >> 5;          // 0..7
  const int xg3 = c >> 3;
  const int cl  = c & 7;

  float lsum = 0.f;

  for (int kc = 0; kc < NCHUNK; ++kc) {
    // ---- h-phase: produce new h-rows into the ring ----
    // 8 column-subtasks per row (4 output cols each), all 256 threads busy.
    const int r0    = (kc == 0) ? -5 : RB * kc + 5;        // local row
    const int ntask = (kc == 0) ? 8 * RING : 8 * RB;       // 336 / 256
    for (int t = tid; t < ntask; t += 256) {
      const int colsub = t & 7;
      const int dr  = t >> 3;
      const int rl  = r0 + dr;                 // local row in [-5, SEGR+4]
      const int ry  = Y0 + rl;                 // global row
      const int rr  = (rl + 5) % RING;         // ring slot row
      const int xg  = colsub >> 1;
      const int sub = colsub & 1;
      const int cbs = X0s + xg * 8 + sub * 4 - 8;  // window col of w20[0], 4-aligned

      float a20[20], b20[20];
      if ((unsigned)ry < (unsigned)IMG) {
        const float* row1 = p1 + (size_t)ry * IMG;
        const float* row2 = p2 + (size_t)ry * IMG;
        if (cbs >= 0 && cbs + 20 <= IMG) {
          #pragma unroll
          for (int i = 0; i < 5; ++i) {
            float4 v1 = *(const float4*)(row1 + cbs + 4 * i);
            float4 v2 = *(const float4*)(row2 + cbs + 4 * i);
            a20[4*i+0] = v1.x; a20[4*i+1] = v1.y; a20[4*i+2] = v1.z; a20[4*i+3] = v1.w;
            b20[4*i+0] = v2.x; b20[4*i+1] = v2.y; b20[4*i+2] = v2.z; b20[4*i+3] = v2.w;
          }
        } else {
          #pragma unroll
          for (int e = 0; e < 20; ++e) {
            int cc = cbs + e;
            bool ok = (unsigned)cc < (unsigned)IMG;
            a20[e] = ok ? row1[cc] : 0.f;
            b20[e] = ok ? row2[cc] : 0.f;
          }
        }
      } else {
        #pragma unroll
        for (int e = 0; e < 20; ++e) { a20[e] = 0.f; b20[e] = 0.f; }
      }

      // two packed output pairs (4 cols) for this subtask
      v2f o0[2], o1[2], o2[2], o3[2], o4[2];
      #pragma unroll
      for (int jp = 0; jp < 2; ++jp) {
        o0[jp] = 0.f; o1[jp] = 0.f; o2[jp] = 0.f; o3[jp] = 0.f; o4[jp] = 0.f;
      }
      // window index i=3..16; m = i - 3 - 2*jp' (independent of sub)
      #pragma unroll
      for (int i = 3; i <= 16; ++i) {
        float va = a20[i], vb = b20[i];
        float pa = va * va, pb = vb * vb, pab = va * vb;
        v2f va2; va2.x = va; va2.y = va;
        v2f vb2; vb2.x = vb; vb2.y = vb;
        v2f pa2; pa2.x = pa; pa2.y = pa;
        v2f pb2; pb2.x = pb; pb2.y = pb;
        v2f pc2; pc2.x = pab; pc2.y = pab;
        if (i - 3 < 12) {                      // jp'=0, m = i-3
          v2f w = wp[i - 3];
          o0[0] = __builtin_elementwise_fma(w, va2, o0[0]);
          o1[0] = __builtin_elementwise_fma(w, vb2, o1[0]);
          o2[0] = __builtin_elementwise_fma(w, pa2, o2[0]);
          o3[0] = __builtin_elementwise_fma(w, pb2, o3[0]);
          o4[0] = __builtin_elementwise_fma(w, pc2, o4[0]);
        }
        if (i - 5 >= 0) {                      // jp'=1, m = i-5 (<=11 always)
          v2f w = wp[i - 5];
          o0[1] = __builtin_elementwise_fma(w, va2, o0[1]);
          o1[1] = __builtin_elementwise_fma(w, vb2, o1[1]);
          o2[1] = __builtin_elementwise_fma(w, pa2, o2[1]);
          o3[1] = __builtin_elementwise_fma(w, pb2, o3[1]);
          o4[1] = __builtin_elementwise_fma(w, pc2, o4[1]);
        }
      }

      const int base  = (xg * RING + rr) * SLOT;
      const int jbase = base + 16 * sub;       // global jpg = 2*sub + jp'
      *(float4*)&sR[jbase]      = make_float4(o0[0].x, o1[0].x, o2[0].x, o3[0].x);
      *(float4*)&sR[jbase + 4]  = make_float4(o0[0].y, o1[0].y, o2[0].y, o3[0].y);
      *(float4*)&sR[jbase + 8]  = make_float4(o0[1].x, o1[1].x, o2[1].x, o3[1].x);
      *(float4*)&sR[jbase + 12] = make_float4(o0[1].y, o1[1].y, o2[1].y, o3[1].y);
      *(float4*)&sR[base + 32 + 4 * sub] =
          make_float4(o4[0].x, o4[0].y, o4[1].x, o4[1].y);
    }
    __syncthreads();

    // ---- v-phase: 4 output rows per thread (2 packed pairs) + SSIM ----
    v2f m1p[2], m2p[2], e11p[2], e22p[2], e12p[2];
    #pragma unroll
    for (int jp = 0; jp < 2; ++jp) {
      m1p[jp] = 0.f; m2p[jp] = 0.f; e11p[jp] = 0.f; e22p[jp] = 0.f; e12p[jp] = 0.f;
    }

    const int y0l = RB * kc + yg * 4;          // local first output row
    int idx = y0l % RING;
    #pragma unroll
    for (int rr = 0; rr < 14; ++rr) {
      const int a = (xg3 * RING + idx) * SLOT;
      float4 v4 = *(const float4*)&sR[a + 4 * cl];
      float  v5 = sR[a + 32 + cl];
      v2f x1; x1.x = v4.x; x1.y = v4.x;
      v2f x2; x2.x = v4.y; x2.y = v4.y;
      v2f x3; x3.x = v4.z; x3.y = v4.z;
      v2f x4; x4.x = v4.w; x4.y = v4.w;
      v2f x5; x5.x = v5;   x5.y = v5;
      if (rr < 12) {                           // jp=0, m = rr
        v2f w = wp[rr];
        m1p[0]  = __builtin_elementwise_fma(w, x1, m1p[0]);
        m2p[0]  = __builtin_elementwise_fma(w, x2, m2p[0]);
        e11p[0] = __builtin_elementwise_fma(w, x3, e11p[0]);
        e22p[0] = __builtin_elementwise_fma(w, x4, e22p[0]);
        e12p[0] = __builtin_elementwise_fma(w, x5, e12p[0]);
      }
      if (rr >= 2) {                           // jp=1, m = rr-2
        v2f w = wp[rr - 2];
        m1p[1]  = __builtin_elementwise_fma(w, x1, m1p[1]);
        m2p[1]  = __builtin_elementwise_fma(w, x2, m2p[1]);
        e11p[1] = __builtin_elementwise_fma(w, x3, e11p[1]);
        e22p[1] = __builtin_elementwise_fma(w, x4, e22p[1]);
        e12p[1] = __builtin_elementwise_fma(w, x5, e12p[1]);
      }
      idx++; if (idx == RING) idx = 0;
    }

    #pragma unroll
    for (int jp = 0; jp < 2; ++jp) {
      v2f m1 = m1p[jp], m2 = m2p[jp];
      v2f m1s = m1 * m1, m2s = m2 * m2, m12 = m1 * m2;
      v2f s11 = e11p[jp] - m1s, s22 = e22p[jp] - m2s, s12 = e12p[jp] - m12;
      v2f num = (2.f * m12 + C1c) * (2.f * s12 + C2c);
      v2f den = (m1s + m2s + C1c) * (s11 + s22 + C2c);
      lsum += (1.f - num.x * __builtin_amdgcn_rcpf(den.x)) * 0.5f;
      lsum += (1.f - num.y * __builtin_amdgcn_rcpf(den.y)) * 0.5f;
    }
    __syncthreads();
  }

  // wave reduce -> block reduce -> ONE atomic per block (6144 total)
  #pragma unroll
  for (int off = 32; off > 0; off >>= 1) lsum += __shfl_down(lsum, off);
  if ((tid & 63) == 0) sR[tid >> 6] = lsum;
  __syncthreads();
  if (tid == 0) atomicAdd(ws, sR[0] + sR[1] + sR[2] + sR[3]);
}

extern "C" void kernel_launch(void* const* d_in, const int* in_sizes, int n_in,
                              void* d_out, int out_size, void* d_ws, size_t ws_size,
                              hipStream_t stream) {
  const float* im1 = (const float*)d_in[0];
  const float* im2 = (const float*)d_in[1];
  const float* gk  = (const float*)d_in[2];
  float* out = (float*)d_out;
  float* ws  = (float*)d_ws;

  hipLaunchKernelGGL(dssim_zero, dim3(1), dim3(1), 0, stream, ws);
  hipLaunchKernelGGL(dssim_main, dim3(NIMG * CTILES * SEGN), dim3(256), 0, stream,
                     im1, im2, gk, ws);
  hipLaunchKernelGGL(dssim_final, dim3(1), dim3(1), 0, stream, ws, out);
}

// Round 5
// 280.157 us; speedup vs baseline: 2.2713x; 1.0156x over previous
//
#include <hip/hip_runtime.h>
#include <math.h>

// DSSIM (mean), B=32 C=3 H=W=512 fp32, separable 11x11 Gaussian.
// R9 = R8 resubmit (R4 infra failure: "container failed twice", kernel
// never ran) + corrected bank rotation found in re-audit:
//  - ALGEBRA: SSIM uses blur(a^2), blur(b^2) only via their SUM:
//    s11+s22 = blur(a^2+b^2) - m1^2 - m2^2. Fields: {A=blur a, B=blur b,
//    S=blur(a^2+b^2), X=blur(ab)} -> 4 fields, exactly one float4 per col.
//    -20% FMA both phases; v-phase ds_read_b32 + 5th broadcast GONE.
//  - SLOT 44 -> 40 (32 payload + 8 pad). Rotation
//    slot_off(col,row,xg) = (4*col + 4*(row&7) + 20*xg) & 31 applied at
//    write and read. With row-base contributing (16*xg + 8*row) mod 32,
//    start banks per 8 consecutive lanes: h-store g -> 4*xg+16*sub+4*g
//    = {0,16,4,20,8,24,12,28} distinct; v-read -> 4*cl+const distinct.
//    Both patterns tile 32 banks once per 8-lane group (conflict-free
//    under the 8-lane/cycle b128 model; falsifiable via counter).
//  - launch bounds stay (256,4): (256,5) caps VGPR ~100 -> catastrophic
//    spill (R5/R6: VGPR=48, up to 1GB scratch traffic).
//  - NO lambdas/helpers (R3: un-inlined helpers demote arrays to scratch).

namespace {
constexpr int IMG = 512;
constexpr int TW = 32;                 // strip width
constexpr int RB = 32;                 // output rows per chunk
constexpr int RING = RB + 10;          // 42 ring rows
constexpr int SLOT = 40;               // floats per (xg, ringrow) slot (32+8 pad)
constexpr int XGN = TW / 8;            // 4 col-groups
constexpr int SEGR = 128;              // rows per block segment
constexpr int NCHUNK = SEGR / RB;      // 4 chunks per segment
constexpr int SEGN = IMG / SEGR;       // 4 segments per strip
constexpr int CTILES = IMG / TW;       // 16 strips per image
constexpr int NIMG = 96;               // 32*3
constexpr float C1c = 1e-4f;
constexpr float C2c = 9e-4f;
constexpr float INV_N = 1.0f / 25165824.0f;  // 1/(96*512*512)
}

typedef float v2f __attribute__((ext_vector_type(2)));

__global__ void dssim_zero(float* ws) { ws[0] = 0.0f; }

__global__ void dssim_final(const float* __restrict__ ws, float* __restrict__ out) {
  out[0] = ws[0] * INV_N;
}

__global__ __launch_bounds__(256, 4) void dssim_main(
    const float* __restrict__ im1, const float* __restrict__ im2,
    const float* __restrict__ gk, float* __restrict__ ws)
{
  __shared__ float sR[XGN * RING * SLOT];   // 26,880 B -> 5-6 blocks/CU

  const int tid = threadIdx.x;
  const int bid = blockIdx.x;
  const int img = bid >> 6;          // 64 blocks per image (16 strips x 4 segs)
  const int rem = bid & 63;
  const int tsx = rem & 15;
  const int seg = rem >> 4;
  const int X0s = tsx * TW;
  const int Y0  = seg * SEGR;

  const float* __restrict__ p1 = im1 + (size_t)img * (IMG * IMG);
  const float* __restrict__ p2 = im2 + (size_t)img * (IMG * IMG);

  // k1[i] = k2d[i][5] / sqrt(k2d[5][5])  (separable, sum(k1)=1)
  float wt[11];
  {
    float ic = 1.0f / sqrtf(gk[5 * 11 + 5]);
    #pragma unroll
    for (int i = 0; i < 11; ++i) wt[i] = gk[i * 11 + 5] * ic;
  }
  // packed weight pairs: wp[m] = {wte(m), wte(m-1)}, wte zero-padded
  v2f wp[12];
  #pragma unroll
  for (int m = 0; m < 12; ++m) {
    float lo = (m <= 10) ? wt[m] : 0.f;
    float hi = (m >= 1) ? wt[m - 1] : 0.f;
    wp[m].x = lo; wp[m].y = hi;
  }

  // v-phase mapping: one column per thread, 4 rows (2 packed pairs)
  const int c   = tid & 31;
  const int yg  = tid >> 5;          // 0..7
  const int xg3 = c >> 3;
  const int cl  = c & 7;

  float lsum = 0.f;

  for (int kc = 0; kc < NCHUNK; ++kc) {
    // ---- h-phase: produce new h-rows into the ring ----
    // 8 column-subtasks per row (4 output cols each), all 256 threads busy.
    const int r0    = (kc == 0) ? -5 : RB * kc + 5;        // local row
    const int ntask = (kc == 0) ? 8 * RING : 8 * RB;       // 336 / 256
    for (int t = tid; t < ntask; t += 256) {
      const int colsub = t & 7;
      const int dr  = t >> 3;
      const int rl  = r0 + dr;                 // local row in [-5, SEGR+4]
      const int ry  = Y0 + rl;                 // global row
      const int rr  = (rl + 5) % RING;         // ring slot row
      const int xg  = colsub >> 1;
      const int sub = colsub & 1;
      const int cbs = X0s + xg * 8 + sub * 4 - 8;  // window col of w20[0], 4-aligned

      float a20[20], b20[20];
      if ((unsigned)ry < (unsigned)IMG) {
        const float* row1 = p1 + (size_t)ry * IMG;
        const float* row2 = p2 + (size_t)ry * IMG;
        if (cbs >= 0 && cbs + 20 <= IMG) {
          #pragma unroll
          for (int i = 0; i < 5; ++i) {
            float4 v1 = *(const float4*)(row1 + cbs + 4 * i);
            float4 v2 = *(const float4*)(row2 + cbs + 4 * i);
            a20[4*i+0] = v1.x; a20[4*i+1] = v1.y; a20[4*i+2] = v1.z; a20[4*i+3] = v1.w;
            b20[4*i+0] = v2.x; b20[4*i+1] = v2.y; b20[4*i+2] = v2.z; b20[4*i+3] = v2.w;
          }
        } else {
          #pragma unroll
          for (int e = 0; e < 20; ++e) {
            int cc = cbs + e;
            bool ok = (unsigned)cc < (unsigned)IMG;
            a20[e] = ok ? row1[cc] : 0.f;
            b20[e] = ok ? row2[cc] : 0.f;
          }
        }
      } else {
        #pragma unroll
        for (int e = 0; e < 20; ++e) { a20[e] = 0.f; b20[e] = 0.f; }
      }

      // 4 fields {A,B,S,X}, two packed output pairs (4 cols) per subtask
      v2f o0[2], o1[2], oS[2], oX[2];
      #pragma unroll
      for (int jp = 0; jp < 2; ++jp) {
        o0[jp] = 0.f; o1[jp] = 0.f; oS[jp] = 0.f; oX[jp] = 0.f;
      }
      // window index i=3..16; m = i - 3 - 2*jp' (independent of sub)
      #pragma unroll
      for (int i = 3; i <= 16; ++i) {
        float va = a20[i], vb = b20[i];
        float px = va * vb;
        float ps = va * va + vb * vb;
        v2f va2; va2.x = va; va2.y = va;
        v2f vb2; vb2.x = vb; vb2.y = vb;
        v2f ps2; ps2.x = ps; ps2.y = ps;
        v2f px2; px2.x = px; px2.y = px;
        if (i - 3 < 12) {                      // jp'=0, m = i-3
          v2f w = wp[i - 3];
          o0[0] = __builtin_elementwise_fma(w, va2, o0[0]);
          o1[0] = __builtin_elementwise_fma(w, vb2, o1[0]);
          oS[0] = __builtin_elementwise_fma(w, ps2, oS[0]);
          oX[0] = __builtin_elementwise_fma(w, px2, oX[0]);
        }
        if (i - 5 >= 0) {                      // jp'=1, m = i-5 (<=11 always)
          v2f w = wp[i - 5];
          o0[1] = __builtin_elementwise_fma(w, va2, o0[1]);
          o1[1] = __builtin_elementwise_fma(w, vb2, o1[1]);
          oS[1] = __builtin_elementwise_fma(w, ps2, oS[1]);
          oX[1] = __builtin_elementwise_fma(w, px2, oX[1]);
        }
      }

      // store: col q = 4*sub + j gets float4{A,B,S,X} at rotated offset
      const int base = (xg * RING + rr) * SLOT;
      const int rot  = 4 * (rr & 7) + 20 * xg;
      const int q0   = 4 * sub;
      *(float4*)&sR[base + ((4 * (q0 + 0) + rot) & 31)] =
          make_float4(o0[0].x, o1[0].x, oS[0].x, oX[0].x);
      *(float4*)&sR[base + ((4 * (q0 + 1) + rot) & 31)] =
          make_float4(o0[0].y, o1[0].y, oS[0].y, oX[0].y);
      *(float4*)&sR[base + ((4 * (q0 + 2) + rot) & 31)] =
          make_float4(o0[1].x, o1[1].x, oS[1].x, oX[1].x);
      *(float4*)&sR[base + ((4 * (q0 + 3) + rot) & 31)] =
          make_float4(o0[1].y, o1[1].y, oS[1].y, oX[1].y);
    }
    __syncthreads();

    // ---- v-phase: 4 output rows per thread (2 packed pairs) + SSIM ----
    v2f m1p[2], m2p[2], eSp[2], eXp[2];
    #pragma unroll
    for (int jp = 0; jp < 2; ++jp) {
      m1p[jp] = 0.f; m2p[jp] = 0.f; eSp[jp] = 0.f; eXp[jp] = 0.f;
    }

    const int y0l = RB * kc + yg * 4;          // local first output row
    int idx = y0l % RING;
    #pragma unroll
    for (int rr = 0; rr < 14; ++rr) {
      const int a = (xg3 * RING + idx) * SLOT +
                    ((4 * cl + 4 * (idx & 7) + 20 * xg3) & 31);
      float4 v4 = *(const float4*)&sR[a];
      v2f x1; x1.x = v4.x; x1.y = v4.x;
      v2f x2; x2.x = v4.y; x2.y = v4.y;
      v2f x3; x3.x = v4.z; x3.y = v4.z;
      v2f x4; x4.x = v4.w; x4.y = v4.w;
      if (rr < 12) {                           // jp=0, m = rr
        v2f w = wp[rr];
        m1p[0] = __builtin_elementwise_fma(w, x1, m1p[0]);
        m2p[0] = __builtin_elementwise_fma(w, x2, m2p[0]);
        eSp[0] = __builtin_elementwise_fma(w, x3, eSp[0]);
        eXp[0] = __builtin_elementwise_fma(w, x4, eXp[0]);
      }
      if (rr >= 2) {                           // jp=1, m = rr-2
        v2f w = wp[rr - 2];
        m1p[1] = __builtin_elementwise_fma(w, x1, m1p[1]);
        m2p[1] = __builtin_elementwise_fma(w, x2, m2p[1]);
        eSp[1] = __builtin_elementwise_fma(w, x3, eSp[1]);
        eXp[1] = __builtin_elementwise_fma(w, x4, eXp[1]);
      }
      idx++; if (idx == RING) idx = 0;
    }

    #pragma unroll
    for (int jp = 0; jp < 2; ++jp) {
      v2f m1 = m1p[jp], m2 = m2p[jp];
      v2f m1s = m1 * m1, m2s = m2 * m2, m12 = m1 * m2;
      v2f sS  = eSp[jp] - m1s - m2s;           // s11 + s22
      v2f s12 = eXp[jp] - m12;
      v2f num = (2.f * m12 + C1c) * (2.f * s12 + C2c);
      v2f den = (m1s + m2s + C1c) * (sS + C2c);
      lsum += (1.f - num.x * __builtin_amdgcn_rcpf(den.x)) * 0.5f;
      lsum += (1.f - num.y * __builtin_amdgcn_rcpf(den.y)) * 0.5f;
    }
    __syncthreads();
  }

  // wave reduce -> block reduce -> ONE atomic per block (6144 total)
  #pragma unroll
  for (int off = 32; off > 0; off >>= 1) lsum += __shfl_down(lsum, off);
  if ((tid & 63) == 0) sR[tid >> 6] = lsum;
  __syncthreads();
  if (tid == 0) atomicAdd(ws, sR[0] + sR[1] + sR[2] + sR[3]);
}

extern "C" void kernel_launch(void* const* d_in, const int* in_sizes, int n_in,
                              void* d_out, int out_size, void* d_ws, size_t ws_size,
                              hipStream_t stream) {
  const float* im1 = (const float*)d_in[0];
  const float* im2 = (const float*)d_in[1];
  const float* gk  = (const float*)d_in[2];
  float* out = (float*)d_out;
  float* ws  = (float*)d_ws;

  hipLaunchKernelGGL(dssim_zero, dim3(1), dim3(1), 0, stream, ws);
  hipLaunchKernelGGL(dssim_main, dim3(NIMG * CTILES * SEGN), dim3(256), 0, stream,
                     im1, im2, gk, ws);
  hipLaunchKernelGGL(dssim_final, dim3(1), dim3(1), 0, stream, ws, out);
}

// Round 6
// 270.138 us; speedup vs baseline: 2.3555x; 1.0371x over previous
//
#include <hip/hip_runtime.h>
#include <math.h>

// DSSIM (mean), B=32 C=3 H=W=512 fp32, separable 11x11 Gaussian.
// R10 = R4's coarse skeleton (RB=64: 8-col h-tasks / 24-float window,
// 8 rows per v-thread -> halo amortized 2.25 reads/row) + R9's wins:
//  - 4-field algebra: {A=blur a, B=blur b, S=blur(a^2+b^2), X=blur(ab)};
//    s11+s22 = S - m1^2 - m2^2. One float4 per column.
//  - SLOT 40 -> 32 (ZERO pad): rotation (4*col + 4*(rr&7) + 8*xg) & 31 is
//    a permutation of {0,4,..,28}, so padding is unnecessary for conflict
//    avoidance. h-store 8-lane group banks {B,B+8,..,B+28} distinct;
//    v-read 4*cl+const distinct. LDS 37.9 KB -> 4 blocks/CU (50% occ),
//    vs R4's 52 KB/3 blocks and R9's fine-grained overhead.
//  - rationale (R9 post-mortem): VALU-issue is the binding pipe (70%busy,
//    ~102us); R4's coarse structure issued only ~71us at 5 fields. This
//    kernel = coarse issue count (x0.8 fields) + 50% occupancy.
//  - grid segmented: SEGR=128 (2 chunks), 6144 blocks, 24/CU, no tail.
//  - launch bounds (256,4): cap 128 VGPR; (256,5) proved catastrophic
//    (R5/R6 spill). Natural demand ~76 (R4) -> no spill expected.
//  - NO lambdas/helpers (R3: un-inlined helpers demote arrays to scratch).

namespace {
constexpr int IMG = 512;
constexpr int TW = 32;                 // strip width
constexpr int RB = 64;                 // output rows per chunk
constexpr int RING = RB + 10;          // 74 ring rows
constexpr int SLOT = 32;               // floats per (xg, ringrow) slot - no pad
constexpr int XGN = TW / 8;            // 4 col-groups
constexpr int SEGR = 128;              // rows per block segment
constexpr int NCHUNK = SEGR / RB;      // 2 chunks per segment
constexpr int SEGN = IMG / SEGR;       // 4 segments per strip
constexpr int CTILES = IMG / TW;       // 16 strips per image
constexpr int NIMG = 96;               // 32*3
constexpr float C1c = 1e-4f;
constexpr float C2c = 9e-4f;
constexpr float INV_N = 1.0f / 25165824.0f;  // 1/(96*512*512)
}

typedef float v2f __attribute__((ext_vector_type(2)));

__global__ void dssim_zero(float* ws) { ws[0] = 0.0f; }

__global__ void dssim_final(const float* __restrict__ ws, float* __restrict__ out) {
  out[0] = ws[0] * INV_N;
}

__global__ __launch_bounds__(256, 4) void dssim_main(
    const float* __restrict__ im1, const float* __restrict__ im2,
    const float* __restrict__ gk, float* __restrict__ ws)
{
  __shared__ float sR[XGN * RING * SLOT];   // 37,888 B -> 4 blocks/CU

  const int tid = threadIdx.x;
  const int bid = blockIdx.x;
  const int img = bid >> 6;          // 64 blocks per image (16 strips x 4 segs)
  const int rem = bid & 63;
  const int tsx = rem & 15;
  const int seg = rem >> 4;
  const int X0s = tsx * TW;
  const int Y0  = seg * SEGR;

  const float* __restrict__ p1 = im1 + (size_t)img * (IMG * IMG);
  const float* __restrict__ p2 = im2 + (size_t)img * (IMG * IMG);

  // k1[i] = k2d[i][5] / sqrt(k2d[5][5])  (separable, sum(k1)=1)
  float wt[11];
  {
    float ic = 1.0f / sqrtf(gk[5 * 11 + 5]);
    #pragma unroll
    for (int i = 0; i < 11; ++i) wt[i] = gk[i * 11 + 5] * ic;
  }
  // packed weight pairs: wp[m] = {wte(m), wte(m-1)}, wte zero-padded
  v2f wp[12];
  #pragma unroll
  for (int m = 0; m < 12; ++m) {
    float lo = (m <= 10) ? wt[m] : 0.f;
    float hi = (m >= 1) ? wt[m - 1] : 0.f;
    wp[m].x = lo; wp[m].y = hi;
  }

  // v-phase mapping: one column per thread, 8 rows (4 packed pairs)
  const int c   = tid & 31;
  const int yg  = tid >> 5;          // 0..7
  const int xg3 = c >> 3;
  const int cl  = c & 7;

  float lsum = 0.f;

  for (int kc = 0; kc < NCHUNK; ++kc) {
    // ---- h-phase: produce new h-rows into the ring (coarse 8-col tasks) --
    const int r0    = (kc == 0) ? -5 : RB * kc + 5;        // local row
    const int ntask = (kc == 0) ? XGN * RING : XGN * RB;   // 296 / 256
    for (int t = tid; t < ntask; t += 256) {
      const int xg = t & 3, dr = t >> 2;
      const int rl = r0 + dr;                  // local row in [-5, SEGR+4]
      const int ry = Y0 + rl;                  // global row
      const int rr = (rl + 5) % RING;          // ring slot row
      const int cb = X0s + xg * 8 - 8;

      float a24[24], b24[24];
      if ((unsigned)ry < (unsigned)IMG) {
        const float* row1 = p1 + (size_t)ry * IMG;
        const float* row2 = p2 + (size_t)ry * IMG;
        if (cb >= 0 && cb + 24 <= IMG) {
          #pragma unroll
          for (int i = 0; i < 6; ++i) {
            float4 v1 = *(const float4*)(row1 + cb + 4 * i);
            float4 v2 = *(const float4*)(row2 + cb + 4 * i);
            a24[4*i+0] = v1.x; a24[4*i+1] = v1.y; a24[4*i+2] = v1.z; a24[4*i+3] = v1.w;
            b24[4*i+0] = v2.x; b24[4*i+1] = v2.y; b24[4*i+2] = v2.z; b24[4*i+3] = v2.w;
          }
        } else {
          #pragma unroll
          for (int e = 0; e < 24; ++e) {
            int cc = cb + e;
            bool ok = (unsigned)cc < (unsigned)IMG;
            a24[e] = ok ? row1[cc] : 0.f;
            b24[e] = ok ? row2[cc] : 0.f;
          }
        }
      } else {
        #pragma unroll
        for (int e = 0; e < 24; ++e) { a24[e] = 0.f; b24[e] = 0.f; }
      }

      // 4 fields {A,B,S,X}, four packed output pairs (8 cols) per task
      v2f o0[4], o1[4], oS[4], oX[4];
      #pragma unroll
      for (int jp = 0; jp < 4; ++jp) {
        o0[jp] = 0.f; o1[jp] = 0.f; oS[jp] = 0.f; oX[jp] = 0.f;
      }
      #pragma unroll
      for (int e = 0; e < 18; ++e) {
        float va = a24[e + 3], vb = b24[e + 3];
        float px = va * vb;
        float ps = va * va + vb * vb;
        v2f va2; va2.x = va; va2.y = va;
        v2f vb2; vb2.x = vb; vb2.y = vb;
        v2f ps2; ps2.x = ps; ps2.y = ps;
        v2f px2; px2.x = px; px2.y = px;
        #pragma unroll
        for (int jp = 0; jp < 4; ++jp) {
          int m = e - 2 * jp;
          if (m >= 0 && m < 12) {
            v2f w = wp[m];
            o0[jp] = __builtin_elementwise_fma(w, va2, o0[jp]);
            o1[jp] = __builtin_elementwise_fma(w, vb2, o1[jp]);
            oS[jp] = __builtin_elementwise_fma(w, ps2, oS[jp]);
            oX[jp] = __builtin_elementwise_fma(w, px2, oX[jp]);
          }
        }
      }

      // store: col q gets float4{A,B,S,X} at rotated offset (perm of 0..28)
      const int base = (xg * RING + rr) * SLOT;
      const int rot  = 4 * (rr & 7) + 8 * xg;
      #pragma unroll
      for (int jp = 0; jp < 4; ++jp) {
        *(float4*)&sR[base + ((4 * (2 * jp) + rot) & 31)] =
            make_float4(o0[jp].x, o1[jp].x, oS[jp].x, oX[jp].x);
        *(float4*)&sR[base + ((4 * (2 * jp + 1) + rot) & 31)] =
            make_float4(o0[jp].y, o1[jp].y, oS[jp].y, oX[jp].y);
      }
    }
    __syncthreads();

    // ---- v-phase: 8 output rows per thread (4 packed pairs) + SSIM ----
    v2f m1p[4], m2p[4], eSp[4], eXp[4];
    #pragma unroll
    for (int jp = 0; jp < 4; ++jp) {
      m1p[jp] = 0.f; m2p[jp] = 0.f; eSp[jp] = 0.f; eXp[jp] = 0.f;
    }

    const int y0l = RB * kc + yg * 8;          // local first output row
    int idx = y0l % RING;
    #pragma unroll
    for (int rr = 0; rr < 18; ++rr) {
      const int a = (xg3 * RING + idx) * SLOT +
                    ((4 * cl + 4 * (idx & 7) + 8 * xg3) & 31);
      float4 v4 = *(const float4*)&sR[a];
      v2f x1; x1.x = v4.x; x1.y = v4.x;
      v2f x2; x2.x = v4.y; x2.y = v4.y;
      v2f x3; x3.x = v4.z; x3.y = v4.z;
      v2f x4; x4.x = v4.w; x4.y = v4.w;
      #pragma unroll
      for (int jp = 0; jp < 4; ++jp) {
        int m = rr - 2 * jp;
        if (m >= 0 && m < 12) {
          v2f w = wp[m];
          m1p[jp] = __builtin_elementwise_fma(w, x1, m1p[jp]);
          m2p[jp] = __builtin_elementwise_fma(w, x2, m2p[jp]);
          eSp[jp] = __builtin_elementwise_fma(w, x3, eSp[jp]);
          eXp[jp] = __builtin_elementwise_fma(w, x4, eXp[jp]);
        }
      }
      idx++; if (idx == RING) idx = 0;
    }

    #pragma unroll
    for (int jp = 0; jp < 4; ++jp) {
      v2f m1 = m1p[jp], m2 = m2p[jp];
      v2f m1s = m1 * m1, m2s = m2 * m2, m12 = m1 * m2;
      v2f sS  = eSp[jp] - m1s - m2s;           // s11 + s22
      v2f s12 = eXp[jp] - m12;
      v2f num = (2.f * m12 + C1c) * (2.f * s12 + C2c);
      v2f den = (m1s + m2s + C1c) * (sS + C2c);
      lsum += (1.f - num.x * __builtin_amdgcn_rcpf(den.x)) * 0.5f;
      lsum += (1.f - num.y * __builtin_amdgcn_rcpf(den.y)) * 0.5f;
    }
    __syncthreads();
  }

  // wave reduce -> block reduce -> ONE atomic per block (6144 total)
  #pragma unroll
  for (int off = 32; off > 0; off >>= 1) lsum += __shfl_down(lsum, off);
  if ((tid & 63) == 0) sR[tid >> 6] = lsum;
  __syncthreads();
  if (tid == 0) atomicAdd(ws, sR[0] + sR[1] + sR[2] + sR[3]);
}

extern "C" void kernel_launch(void* const* d_in, const int* in_sizes, int n_in,
                              void* d_out, int out_size, void* d_ws, size_t ws_size,
                              hipStream_t stream) {
  const float* im1 = (const float*)d_in[0];
  const float* im2 = (const float*)d_in[1];
  const float* gk  = (const float*)d_in[2];
  float* out = (float*)d_out;
  float* ws  = (float*)d_ws;

  hipLaunchKernelGGL(dssim_zero, dim3(1), dim3(1), 0, stream, ws);
  hipLaunchKernelGGL(dssim_main, dim3(NIMG * CTILES * SEGN), dim3(256), 0, stream,
                     im1, im2, gk, ws);
  hipLaunchKernelGGL(dssim_final, dim3(1), dim3(1), 0, stream, ws, out);
}

// Round 7
// 267.088 us; speedup vs baseline: 2.3824x; 1.0114x over previous
//
#include <hip/hip_runtime.h>
#include <math.h>

// DSSIM (mean), B=32 C=3 H=W=512 fp32, separable 11x11 Gaussian.
// R11 = R10 geometry (RB=64 ring, SLOT=32+rotation, 6144 blocks, (256,4))
// with the packing axis FLIPPED to kill broadcast movs (R10 post-mortem:
// VALU-issue 82us of 134us, ~70us is movs/addr, conv FMA only ~14us):
//  - pack over FIELDS not columns: d01={a,b}, d23={a^2+b^2, ab}; weight is
//    the splat operand (w2[t], both halves equal, built once at init).
//  - v-phase: LDS float4 {A,B,S,X} = the two packed operands directly
//    (v4.xy, v4.zw) -> ZERO unpacking movs. 2 pk-fma per (row,tap).
//  - h-phase: pairs built once per elem (3 ops), reused across 8 cols;
//    scalar-j tap loop t=e-j in [0,11) -> 176 pk-fma/task (was 192) and
//    no per-elem splat movs. Loads interleaved per float4-group (no
//    a24/b24 arrays) -> live regs ~75, no spill at the (256,4) cap.
//  - store as 2x ds_write_b64 (oab, osx pairs directly): -16 movs/task
//    for +8 LDS cycles; VALU is the binding pipe.
//  - conflicts left alone this round (R9->R10: 5.5M->10.6M yet 8% faster;
//    mostly benign b128 phasing) - only the packing axis varies.
//  - NO lambdas/helpers (R3: un-inlined helpers demote arrays to scratch).

namespace {
constexpr int IMG = 512;
constexpr int TW = 32;                 // strip width
constexpr int RB = 64;                 // output rows per chunk
constexpr int RING = RB + 10;          // 74 ring rows
constexpr int SLOT = 32;               // floats per (xg, ringrow) slot - no pad
constexpr int XGN = TW / 8;            // 4 col-groups
constexpr int SEGR = 128;              // rows per block segment
constexpr int NCHUNK = SEGR / RB;      // 2 chunks per segment
constexpr int SEGN = IMG / SEGR;       // 4 segments per strip
constexpr int CTILES = IMG / TW;       // 16 strips per image
constexpr int NIMG = 96;               // 32*3
constexpr float C1c = 1e-4f;
constexpr float C2c = 9e-4f;
constexpr float INV_N = 1.0f / 25165824.0f;  // 1/(96*512*512)
}

typedef float v2f __attribute__((ext_vector_type(2)));

__global__ void dssim_zero(float* ws) { ws[0] = 0.0f; }

__global__ void dssim_final(const float* __restrict__ ws, float* __restrict__ out) {
  out[0] = ws[0] * INV_N;
}

// accumulate one window elem (E = window_idx - 3, compile-time const) into
// the 8 column accumulators. d01={a,b}, d23={a2+b2, ab}; weight splat w2[t].
#define ACC_E(E, VA, VB) do {                                              \
    const int e_ = (E);                                                    \
    if (e_ >= 0 && e_ < 18) {                                              \
      float va_ = (VA), vb_ = (VB);                                        \
      float pab_ = va_ * vb_;                                              \
      float ps_  = __builtin_fmaf(vb_, vb_, va_ * va_);                    \
      v2f d01_; d01_.x = va_; d01_.y = vb_;                                \
      v2f d23_; d23_.x = ps_; d23_.y = pab_;                               \
      _Pragma("unroll")                                                    \
      for (int j_ = 0; j_ < 8; ++j_) {                                     \
        const int t_ = e_ - j_;                                            \
        if (t_ >= 0 && t_ < 11) {                                          \
          oab[j_] = __builtin_elementwise_fma(w2[t_], d01_, oab[j_]);      \
          osx[j_] = __builtin_elementwise_fma(w2[t_], d23_, osx[j_]);      \
        }                                                                  \
      }                                                                    \
    }                                                                      \
  } while (0)

__global__ __launch_bounds__(256, 4) void dssim_main(
    const float* __restrict__ im1, const float* __restrict__ im2,
    const float* __restrict__ gk, float* __restrict__ ws)
{
  __shared__ float sR[XGN * RING * SLOT];   // 37,888 B -> 4 blocks/CU

  const int tid = threadIdx.x;
  const int bid = blockIdx.x;
  const int img = bid >> 6;          // 64 blocks per image (16 strips x 4 segs)
  const int rem = bid & 63;
  const int tsx = rem & 15;
  const int seg = rem >> 4;
  const int X0s = tsx * TW;
  const int Y0  = seg * SEGR;

  const float* __restrict__ p1 = im1 + (size_t)img * (IMG * IMG);
  const float* __restrict__ p2 = im2 + (size_t)img * (IMG * IMG);

  // k1[i] = k2d[i][5] / sqrt(k2d[5][5])  (separable, sum(k1)=1)
  // weight SPLATS: w2[t].x == w2[t].y == wt[t]
  v2f w2[11];
  {
    float ic = 1.0f / sqrtf(gk[5 * 11 + 5]);
    #pragma unroll
    for (int t = 0; t < 11; ++t) {
      float w = gk[t * 11 + 5] * ic;
      w2[t].x = w; w2[t].y = w;
    }
  }

  // v-phase mapping: one column per thread, 8 rows
  const int c   = tid & 31;
  const int yg  = tid >> 5;          // 0..7
  const int xg3 = c >> 3;
  const int cl  = c & 7;

  float lsum = 0.f;

  for (int kc = 0; kc < NCHUNK; ++kc) {
    // ---- h-phase: produce new h-rows into the ring (coarse 8-col tasks) --
    const int r0    = (kc == 0) ? -5 : RB * kc + 5;        // local row
    const int ntask = (kc == 0) ? XGN * RING : XGN * RB;   // 296 / 256
    for (int t = tid; t < ntask; t += 256) {
      const int xg = t & 3, dr = t >> 2;
      const int rl = r0 + dr;                  // local row in [-5, SEGR+4]
      const int ry = Y0 + rl;                  // global row
      const int rr = (rl + 5) % RING;          // ring slot row
      const int cb = X0s + xg * 8 - 8;

      // col-j accumulators: oab[j]={A,B}, osx[j]={S,X}
      v2f oab[8], osx[8];
      #pragma unroll
      for (int j = 0; j < 8; ++j) { oab[j] = 0.f; osx[j] = 0.f; }

      if ((unsigned)ry < (unsigned)IMG) {
        const float* row1 = p1 + (size_t)ry * IMG;
        const float* row2 = p2 + (size_t)ry * IMG;
        if (cb >= 0 && cb + 24 <= IMG) {
          // interior: load one float4 pair per group, accumulate, move on
          #pragma unroll
          for (int g = 0; g < 6; ++g) {
            float4 v1 = *(const float4*)(row1 + cb + 4 * g);
            float4 v2 = *(const float4*)(row2 + cb + 4 * g);
            ACC_E(4 * g - 3, v1.x, v2.x);
            ACC_E(4 * g - 2, v1.y, v2.y);
            ACC_E(4 * g - 1, v1.z, v2.z);
            ACC_E(4 * g + 0, v1.w, v2.w);
          }
        } else {
          // boundary: scalar guarded loads (only window idx 3..20 matter)
          #pragma unroll
          for (int i = 3; i <= 20; ++i) {
            int cc = cb + i;
            float va = 0.f, vb = 0.f;
            if ((unsigned)cc < (unsigned)IMG) { va = row1[cc]; vb = row2[cc]; }
            ACC_E(i - 3, va, vb);
          }
        }
      }

      // store: col j -> {A,B} then {S,X} as two b64 at rotated quad offset
      const int base = (xg * RING + rr) * SLOT;
      const int rot  = 4 * (rr & 7) + 8 * xg;
      #pragma unroll
      for (int j = 0; j < 8; ++j) {
        const int a = base + ((4 * j + rot) & 31);
        *(v2f*)&sR[a]     = oab[j];
        *(v2f*)&sR[a + 2] = osx[j];
      }
    }
    __syncthreads();

    // ---- v-phase: 8 output rows per thread + SSIM ----
    v2f mab[8], msx[8];
    #pragma unroll
    for (int j = 0; j < 8; ++j) { mab[j] = 0.f; msx[j] = 0.f; }

    const int y0l = RB * kc + yg * 8;          // local first output row
    int idx = y0l % RING;
    #pragma unroll
    for (int rr = 0; rr < 18; ++rr) {
      const int a = (xg3 * RING + idx) * SLOT +
                    ((4 * cl + 4 * (idx & 7) + 8 * xg3) & 31);
      float4 v4 = *(const float4*)&sR[a];
      v2f d01; d01.x = v4.x; d01.y = v4.y;     // {A,B} - already adjacent
      v2f d23; d23.x = v4.z; d23.y = v4.w;     // {S,X} - already adjacent
      #pragma unroll
      for (int j = 0; j < 8; ++j) {
        const int t = rr - j;
        if (t >= 0 && t < 11) {
          mab[j] = __builtin_elementwise_fma(w2[t], d01, mab[j]);
          msx[j] = __builtin_elementwise_fma(w2[t], d23, msx[j]);
        }
      }
      idx++; if (idx == RING) idx = 0;
    }

    #pragma unroll
    for (int j = 0; j < 8; ++j) {
      float m1 = mab[j].x, m2 = mab[j].y;
      float eS = msx[j].x, eX = msx[j].y;
      float m1s = m1 * m1, m2s = m2 * m2, m12 = m1 * m2;
      float sS  = eS - m1s - m2s;              // s11 + s22
      float s12 = eX - m12;
      float num = (2.f * m12 + C1c) * (2.f * s12 + C2c);
      float den = (m1s + m2s + C1c) * (sS + C2c);
      lsum += (1.f - num * __builtin_amdgcn_rcpf(den)) * 0.5f;
    }
    __syncthreads();
  }

  // wave reduce -> block reduce -> ONE atomic per block (6144 total)
  #pragma unroll
  for (int off = 32; off > 0; off >>= 1) lsum += __shfl_down(lsum, off);
  if ((tid & 63) == 0) sR[tid >> 6] = lsum;
  __syncthreads();
  if (tid == 0) atomicAdd(ws, sR[0] + sR[1] + sR[2] + sR[3]);
}

extern "C" void kernel_launch(void* const* d_in, const int* in_sizes, int n_in,
                              void* d_out, int out_size, void* d_ws, size_t ws_size,
                              hipStream_t stream) {
  const float* im1 = (const float*)d_in[0];
  const float* im2 = (const float*)d_in[1];
  const float* gk  = (const float*)d_in[2];
  float* out = (float*)d_out;
  float* ws  = (float*)d_ws;

  hipLaunchKernelGGL(dssim_zero, dim3(1), dim3(1), 0, stream, ws);
  hipLaunchKernelGGL(dssim_main, dim3(NIMG * CTILES * SEGN), dim3(256), 0, stream,
                     im1, im2, gk, ws);
  hipLaunchKernelGGL(dssim_final, dim3(1), dim3(1), 0, stream, ws, out);
}